// Round 3
// baseline (651.916 us; speedup 1.0000x reference)
//
#include <hip/hip_runtime.h>
#include <hip/hip_bf16.h>

// BoxModelTriples: M=8, B=200000, D=32, N=100000
// box_param: (M, B, 2, D) float32 ; weights: (M,) ; ids: (N,4) int32 ; out: (N,)
//
// R3: two-pass. Pass 1 transposes + clips the box table into d_ws as
// (B, M, 2, D) fp32 (409.6 MB) so one box = one contiguous 2 KB block.
// Pass 2 gathers 3 contiguous 2 KB blocks per row instead of 24 scattered
// 256 B segments -> near-streaming gather efficiency.

#define MM 8
#define BB 200000
#define DD 32

// ---------------- Pass 1: transpose (M,B,2,D) -> (B,M,2,D), clip to [0,1] ----
// 102.4M floats = 25.6M float4 = 100000 blocks x 256 threads exactly.
__global__ __launch_bounds__(256) void transpose_clip_kernel(
    const float4* __restrict__ in, float4* __restrict__ out)
{
    const int idx = blockIdx.x * 256 + threadIdx.x;   // dst float4 index
    const int t = idx & 7;          // d-chunk
    const int s = (idx >> 3) & 1;   // z/Z
    const int m = (idx >> 4) & 7;
    const int b = idx >> 7;
    float4 v = in[((m * BB + b) * 2 + s) * 8 + t];
    v.x = fminf(fmaxf(v.x, 0.f), 1.f);
    v.y = fminf(fmaxf(v.y, 0.f), 1.f);
    v.z = fminf(fmaxf(v.z, 0.f), 1.f);
    v.w = fminf(fmaxf(v.w, 0.f), 1.f);
    out[idx] = v;                    // fully coalesced streaming write
}

// ---------------- Pass 2: gather from (B,M,2,D) -------------------------------
// One wave per row. lane: m = lane>>3, t = lane&7 (d = 4t..4t+3).
// Box i occupies tbox[i*512 .. i*512+511] (2 KB contiguous).
__global__ __launch_bounds__(256) void gather_kernel(
    const float* __restrict__ tbox,  // (B,M,2,D) pre-clipped
    const float* __restrict__ wts,   // (M,)
    const int*   __restrict__ ids,   // (N,4)
    float*       __restrict__ out,   // (N,)
    int N)
{
    const int lane = threadIdx.x & 63;
    const int wave = threadIdx.x >> 6;
    const int n = blockIdx.x * (blockDim.x >> 6) + wave;
    if (n >= N) return;

    const int m = lane >> 3;
    const int t = lane & 7;

    const int4 idv = ((const int4*)ids)[n];
    const int i0 = idv.x, i1 = idv.y, i2 = idv.z;

    const int baseA = i0 * (MM * 2 * DD) + m * (2 * DD) + t * 4;
    const int baseB = i1 * (MM * 2 * DD) + m * (2 * DD) + t * 4;
    const int baseC = i2 * (MM * 2 * DD) + m * (2 * DD) + t * 4;

    const float4 zA4 = *(const float4*)(tbox + baseA);
    const float4 ZA4 = *(const float4*)(tbox + baseA + DD);
    const float4 zB4 = *(const float4*)(tbox + baseB);
    const float4 ZB4 = *(const float4*)(tbox + baseB + DD);
    const float4 zC4 = *(const float4*)(tbox + baseC);
    const float4 ZC4 = *(const float4*)(tbox + baseC + DD);

    // per-lane softmax weight for this m
    float wl = wts[m];
    float wmax = wl;
    #pragma unroll
    for (int off = 8; off < 64; off <<= 1) wmax = fmaxf(wmax, __shfl_xor(wmax, off));
    float ew = __expf(wl - wmax);
    float esum = ew;
    #pragma unroll
    for (int off = 8; off < 64; off <<= 1) esum += __shfl_xor(esum, off);
    const float w = ew / esum;

    float pA = 1.f, pAB = 1.f, pABC = 1.f;
    #define COMP(c) { \
        const float zab  = fmaxf(zA4.c, zB4.c),  Zab  = fminf(ZA4.c, ZB4.c); \
        const float zabc = fmaxf(zab, zC4.c),    Zabc = fminf(Zab, ZC4.c); \
        pA   *= fmaxf(ZA4.c - zA4.c, 0.f); \
        pAB  *= fmaxf(Zab   - zab,   0.f); \
        pABC *= fmaxf(Zabc  - zabc,  0.f); \
    }
    COMP(x) COMP(y) COMP(z) COMP(w)
    #undef COMP

    #pragma unroll
    for (int off = 1; off < 8; off <<= 1) {
        pA   *= __shfl_xor(pA,   off);
        pAB  *= __shfl_xor(pAB,  off);
        pABC *= __shfl_xor(pABC, off);
    }

    float sA = w * pA, sAB = w * pAB, sABC = w * pABC;
    #pragma unroll
    for (int off = 8; off < 64; off <<= 1) {
        sA   += __shfl_xor(sA,   off);
        sAB  += __shfl_xor(sAB,  off);
        sABC += __shfl_xor(sABC, off);
    }

    const float TINY = 1.1754943508222875e-38f;
    float res;
    if (i1 != i2)      res = (sABC + TINY) / (sAB + TINY);
    else if (i0 != i1) res = (sAB  + TINY) / (sA  + TINY);
    else               res = sA;

    if (lane == 0) out[n] = res;
}

// ---------------- Fallback: direct gather from native layout ------------------
__global__ __launch_bounds__(256) void direct_kernel(
    const float* __restrict__ box,   // (M,B,2,D)
    const float* __restrict__ wts,
    const int*   __restrict__ ids,
    float*       __restrict__ out,
    int N)
{
    const int lane = threadIdx.x & 63;
    const int wave = threadIdx.x >> 6;
    const int n = blockIdx.x * (blockDim.x >> 6) + wave;
    if (n >= N) return;

    const int m = lane >> 3;
    const int t = lane & 7;

    const int4 idv = ((const int4*)ids)[n];
    const int i0 = idv.x, i1 = idv.y, i2 = idv.z;

    const int baseA = (m * BB + i0) * (2 * DD) + t * 4;
    const int baseB = (m * BB + i1) * (2 * DD) + t * 4;
    const int baseC = (m * BB + i2) * (2 * DD) + t * 4;

    const float4 zA4 = *(const float4*)(box + baseA);
    const float4 ZA4 = *(const float4*)(box + baseA + DD);
    const float4 zB4 = *(const float4*)(box + baseB);
    const float4 ZB4 = *(const float4*)(box + baseB + DD);
    const float4 zC4 = *(const float4*)(box + baseC);
    const float4 ZC4 = *(const float4*)(box + baseC + DD);

    float wl = wts[m];
    float wmax = wl;
    #pragma unroll
    for (int off = 8; off < 64; off <<= 1) wmax = fmaxf(wmax, __shfl_xor(wmax, off));
    float ew = __expf(wl - wmax);
    float esum = ew;
    #pragma unroll
    for (int off = 8; off < 64; off <<= 1) esum += __shfl_xor(esum, off);
    const float w = ew / esum;

    float pA = 1.f, pAB = 1.f, pABC = 1.f;
    #define CL(x) fminf(fmaxf((x), 0.f), 1.f)
    #define COMP(c) { \
        const float za = CL(zA4.c), Za = CL(ZA4.c); \
        const float zb = CL(zB4.c), Zb = CL(ZB4.c); \
        const float zc = CL(zC4.c), Zc = CL(ZC4.c); \
        const float zab  = fmaxf(za, zb),  Zab  = fminf(Za, Zb); \
        const float zabc = fmaxf(zab, zc), Zabc = fminf(Zab, Zc); \
        pA   *= fmaxf(Za   - za,   0.f); \
        pAB  *= fmaxf(Zab  - zab,  0.f); \
        pABC *= fmaxf(Zabc - zabc, 0.f); \
    }
    COMP(x) COMP(y) COMP(z) COMP(w)
    #undef COMP
    #undef CL

    #pragma unroll
    for (int off = 1; off < 8; off <<= 1) {
        pA   *= __shfl_xor(pA,   off);
        pAB  *= __shfl_xor(pAB,  off);
        pABC *= __shfl_xor(pABC, off);
    }

    float sA = w * pA, sAB = w * pAB, sABC = w * pABC;
    #pragma unroll
    for (int off = 8; off < 64; off <<= 1) {
        sA   += __shfl_xor(sA,   off);
        sAB  += __shfl_xor(sAB,  off);
        sABC += __shfl_xor(sABC, off);
    }

    const float TINY = 1.1754943508222875e-38f;
    float res;
    if (i1 != i2)      res = (sABC + TINY) / (sAB + TINY);
    else if (i0 != i1) res = (sAB  + TINY) / (sA  + TINY);
    else               res = sA;

    if (lane == 0) out[n] = res;
}

extern "C" void kernel_launch(void* const* d_in, const int* in_sizes, int n_in,
                              void* d_out, int out_size, void* d_ws, size_t ws_size,
                              hipStream_t stream) {
    const float* box = (const float*)d_in[0];
    const float* wts = (const float*)d_in[1];
    const int*   ids = (const int*)d_in[2];
    float* out = (float*)d_out;
    const int N = out_size;  // 100000

    const size_t tbox_bytes = (size_t)BB * MM * 2 * DD * sizeof(float); // 409.6 MB
    const int wavesPerBlock = 4;
    const int blocks = (N + wavesPerBlock - 1) / wavesPerBlock;

    if (ws_size >= tbox_bytes) {
        float* tbox = (float*)d_ws;
        // 25.6M float4 / 256 threads = 100000 blocks (exact)
        transpose_clip_kernel<<<100000, 256, 0, stream>>>(
            (const float4*)box, (float4*)tbox);
        gather_kernel<<<blocks, 256, 0, stream>>>(tbox, wts, ids, out, N);
    } else {
        direct_kernel<<<blocks, 256, 0, stream>>>(box, wts, ids, out, N);
    }
}

// Round 4
// 585.287 us; speedup vs baseline: 1.1138x; 1.1138x over previous
//
#include <hip/hip_runtime.h>
#include <hip/hip_bf16.h>
#include <hip/hip_fp16.h>

// BoxModelTriples: M=8, B=200000, D=32, N=100000
// box_param: (M, B, 2, D) float32 ; weights: (M,) ; ids: (N,4) int32 ; out: (N,)
//
// R4: compress + transpose the table to fp16 interleaved (z,Z) pairs:
// tbox[b][m][d] = half2(clip(z), clip(Z))  -> (B, M, D) half2 = 204.8 MB.
// - gather traffic halves (614 -> 307 MB)
// - table fits in 256 MB Infinity Cache (L3-resident after prep pass)
// - one box = 1 KB contiguous = one dwordx4 per lane; (z,Z) lane-local.

#define MM 8
#define BB 200000
#define DD 32

// ---------------- Pass 1: (M,B,2,D) fp32 -> (B,M,D) half2, clipped ----------
// One thread per 4-d chunk: B*M*8 = 12.8M threads, 16 B store each.
__global__ __launch_bounds__(256) void convert_kernel(
    const float* __restrict__ in, __half2* __restrict__ outp)
{
    const int idx = blockIdx.x * 256 + threadIdx.x;
    const int t = idx & 7;          // d-quad: d = 4t..4t+3
    const int m = (idx >> 3) & 7;
    const int b = idx >> 6;

    const int zoff = (m * BB + b) * (2 * DD) + t * 4;
    const float4 z4 = *(const float4*)(in + zoff);
    const float4 Z4 = *(const float4*)(in + zoff + DD);

    #define CL(x) fminf(fmaxf((x), 0.f), 1.f)
    __half2 o[4];
    o[0] = __halves2half2(__float2half(CL(z4.x)), __float2half(CL(Z4.x)));
    o[1] = __halves2half2(__float2half(CL(z4.y)), __float2half(CL(Z4.y)));
    o[2] = __halves2half2(__float2half(CL(z4.z)), __float2half(CL(Z4.z)));
    o[3] = __halves2half2(__float2half(CL(z4.w)), __float2half(CL(Z4.w)));
    #undef CL

    const int oidx = (b * MM + m) * DD + t * 4;   // half2 units, 16B-aligned
    *(float4*)(outp + oidx) = *(const float4*)o;  // fully coalesced
}

// ---------------- Pass 2: gather from (B,M,D) half2 --------------------------
// One wave per row. lane: m = lane>>3, t = lane&7 (d = 4t..4t+3).
// Box i = tbox[i*256 .. i*256+255] half2 (1 KB). 3 dwordx4 loads per lane.
__global__ __launch_bounds__(256) void gather16_kernel(
    const __half2* __restrict__ tbox,  // (B,M,D) pre-clipped
    const float*   __restrict__ wts,   // (M,)
    const int*     __restrict__ ids,   // (N,4)
    float*         __restrict__ out,   // (N,)
    int N)
{
    const int lane = threadIdx.x & 63;
    const int wave = threadIdx.x >> 6;
    const int n = blockIdx.x * (blockDim.x >> 6) + wave;
    if (n >= N) return;

    const int m = lane >> 3;
    const int t = lane & 7;
    const int sub = m * DD + t * 4;    // half2 offset within a box

    const int4 idv = ((const int4*)ids)[n];
    const int i0 = idv.x, i1 = idv.y, i2 = idv.z;

    const float4 a4 = *(const float4*)(tbox + i0 * (MM * DD) + sub);
    const float4 b4 = *(const float4*)(tbox + i1 * (MM * DD) + sub);
    const float4 c4 = *(const float4*)(tbox + i2 * (MM * DD) + sub);
    const __half2* av = (const __half2*)&a4;
    const __half2* bv = (const __half2*)&b4;
    const __half2* cv = (const __half2*)&c4;

    // per-lane softmax weight for this m
    float wl = wts[m];
    float wmax = wl;
    #pragma unroll
    for (int off = 8; off < 64; off <<= 1) wmax = fmaxf(wmax, __shfl_xor(wmax, off));
    float ew = __expf(wl - wmax);
    float esum = ew;
    #pragma unroll
    for (int off = 8; off < 64; off <<= 1) esum += __shfl_xor(esum, off);
    const float w = ew / esum;

    float pA = 1.f, pAB = 1.f, pABC = 1.f;
    #pragma unroll
    for (int c = 0; c < 4; ++c) {
        const float za = __low2float(av[c]),  Za = __high2float(av[c]);
        const float zb = __low2float(bv[c]),  Zb = __high2float(bv[c]);
        const float zc = __low2float(cv[c]),  Zc = __high2float(cv[c]);
        const float zab  = fmaxf(za, zb),  Zab  = fminf(Za, Zb);
        const float zabc = fmaxf(zab, zc), Zabc = fminf(Zab, Zc);
        pA   *= fmaxf(Za   - za,   0.f);
        pAB  *= fmaxf(Zab  - zab,  0.f);
        pABC *= fmaxf(Zabc - zabc, 0.f);
    }

    // product over t (8 lanes per m group)
    #pragma unroll
    for (int off = 1; off < 8; off <<= 1) {
        pA   *= __shfl_xor(pA,   off);
        pAB  *= __shfl_xor(pAB,  off);
        pABC *= __shfl_xor(pABC, off);
    }

    // weighted sum over m
    float sA = w * pA, sAB = w * pAB, sABC = w * pABC;
    #pragma unroll
    for (int off = 8; off < 64; off <<= 1) {
        sA   += __shfl_xor(sA,   off);
        sAB  += __shfl_xor(sAB,  off);
        sABC += __shfl_xor(sABC, off);
    }

    const float TINY = 1.1754943508222875e-38f;
    float res;
    if (i1 != i2)      res = (sABC + TINY) / (sAB + TINY);
    else if (i0 != i1) res = (sAB  + TINY) / (sA  + TINY);
    else               res = sA;

    if (lane == 0) out[n] = res;
}

// ---------------- Fallback: direct fp32 gather (R2) ---------------------------
__global__ __launch_bounds__(256) void direct_kernel(
    const float* __restrict__ box,
    const float* __restrict__ wts,
    const int*   __restrict__ ids,
    float*       __restrict__ out,
    int N)
{
    const int lane = threadIdx.x & 63;
    const int wave = threadIdx.x >> 6;
    const int n = blockIdx.x * (blockDim.x >> 6) + wave;
    if (n >= N) return;

    const int m = lane >> 3;
    const int t = lane & 7;

    const int4 idv = ((const int4*)ids)[n];
    const int i0 = idv.x, i1 = idv.y, i2 = idv.z;

    const int baseA = (m * BB + i0) * (2 * DD) + t * 4;
    const int baseB = (m * BB + i1) * (2 * DD) + t * 4;
    const int baseC = (m * BB + i2) * (2 * DD) + t * 4;

    const float4 zA4 = *(const float4*)(box + baseA);
    const float4 ZA4 = *(const float4*)(box + baseA + DD);
    const float4 zB4 = *(const float4*)(box + baseB);
    const float4 ZB4 = *(const float4*)(box + baseB + DD);
    const float4 zC4 = *(const float4*)(box + baseC);
    const float4 ZC4 = *(const float4*)(box + baseC + DD);

    float wl = wts[m];
    float wmax = wl;
    #pragma unroll
    for (int off = 8; off < 64; off <<= 1) wmax = fmaxf(wmax, __shfl_xor(wmax, off));
    float ew = __expf(wl - wmax);
    float esum = ew;
    #pragma unroll
    for (int off = 8; off < 64; off <<= 1) esum += __shfl_xor(esum, off);
    const float w = ew / esum;

    float pA = 1.f, pAB = 1.f, pABC = 1.f;
    #define CL(x) fminf(fmaxf((x), 0.f), 1.f)
    #define COMP(c) { \
        const float za = CL(zA4.c), Za = CL(ZA4.c); \
        const float zb = CL(zB4.c), Zb = CL(ZB4.c); \
        const float zc = CL(zC4.c), Zc = CL(ZC4.c); \
        const float zab  = fmaxf(za, zb),  Zab  = fminf(Za, Zb); \
        const float zabc = fmaxf(zab, zc), Zabc = fminf(Zab, Zc); \
        pA   *= fmaxf(Za   - za,   0.f); \
        pAB  *= fmaxf(Zab  - zab,  0.f); \
        pABC *= fmaxf(Zabc - zabc, 0.f); \
    }
    COMP(x) COMP(y) COMP(z) COMP(w)
    #undef COMP
    #undef CL

    #pragma unroll
    for (int off = 1; off < 8; off <<= 1) {
        pA   *= __shfl_xor(pA,   off);
        pAB  *= __shfl_xor(pAB,  off);
        pABC *= __shfl_xor(pABC, off);
    }

    float sA = w * pA, sAB = w * pAB, sABC = w * pABC;
    #pragma unroll
    for (int off = 8; off < 64; off <<= 1) {
        sA   += __shfl_xor(sA,   off);
        sAB  += __shfl_xor(sAB,  off);
        sABC += __shfl_xor(sABC, off);
    }

    const float TINY = 1.1754943508222875e-38f;
    float res;
    if (i1 != i2)      res = (sABC + TINY) / (sAB + TINY);
    else if (i0 != i1) res = (sAB  + TINY) / (sA  + TINY);
    else               res = sA;

    if (lane == 0) out[n] = res;
}

extern "C" void kernel_launch(void* const* d_in, const int* in_sizes, int n_in,
                              void* d_out, int out_size, void* d_ws, size_t ws_size,
                              hipStream_t stream) {
    const float* box = (const float*)d_in[0];
    const float* wts = (const float*)d_in[1];
    const int*   ids = (const int*)d_in[2];
    float* out = (float*)d_out;
    const int N = out_size;  // 100000

    const size_t tbox_bytes = (size_t)BB * MM * DD * sizeof(__half2); // 204.8 MB
    const int wavesPerBlock = 4;
    const int blocks = (N + wavesPerBlock - 1) / wavesPerBlock;

    if (ws_size >= tbox_bytes) {
        __half2* tbox = (__half2*)d_ws;
        // B*M*8 = 12.8M threads / 256 = 50000 blocks (exact)
        convert_kernel<<<50000, 256, 0, stream>>>(box, tbox);
        gather16_kernel<<<blocks, 256, 0, stream>>>(tbox, wts, ids, out, N);
    } else {
        direct_kernel<<<blocks, 256, 0, stream>>>(box, wts, ids, out, N);
    }
}